// Round 2
// baseline (888.942 us; speedup 1.0000x reference)
//
#include <hip/hip_runtime.h>

// DirectionalSeparableConv2D — LDS-tiled fused kernel.
// x: (128,128,48,48) f32 NCHW. out: (128,128,48,48) f32.
// in ch: [0,32)=cen, [32,56)=h, [56,80)=v, [80,104)=d1, [104,128)=d2
// Block = 384 threads = (b, 8 rows x 48 cols) tile, 1 pixel/thread.
// Per channel-group: coalesced float4 stage into LDS (zero-filled halo rows +
// zero column at w=48 so conv needs NO boundary masks), conv from LDS,
// register-only mix-fold overlapped with next group's staging loads.

namespace {
constexpr int HH = 48, WW = 48;
constexpr int CEN_IN = 32, DIR_IN = 24, CEN_OUT = 32, DIR_OUT = 24;
constexpr int C_IN = 128, C_OUT = 128, HW = HH * WW;
constexpr int TH = 8;            // output rows per block
constexpr int RH = TH + 4;       // staged rows incl. halo (12)
constexpr int RW = 52;           // LDS row stride (dwords): 16B-aligned rows, col 48 = zero
constexpr int NT = TH * WW;      // 384 threads
}

// Stage C channels [c0, c0+C) of this batch image into xs[0..C)[12][52].
// Rows are global h0-2 .. h0+9; out-of-range rows stored as zeros.
// Column 48..51 zeroed (zero column for w-boundary taps).
template <int C>
__device__ __forceinline__ void stage_group(float (*__restrict__ xs)[RH][RW],
                                            const float* __restrict__ xb,
                                            int c0, int h0, int tid) {
    if (tid < C * RH) {
        int c = tid / RH, r = tid % RH;
        *(float4*)&xs[c][r][48] = float4{0.f, 0.f, 0.f, 0.f};
    }
    constexpr int ITEMS = C * RH * 12;   // float4 quads of real data
    constexpr int PT = ITEMS / NT;       // 6 (C=16) or 9 (C=24), exact
#pragma unroll
    for (int k = 0; k < PT; ++k) {
        int i = tid + k * NT;
        int q = i % 12;
        int rc = i / 12;
        int r = rc % RH;
        int c = rc / RH;
        int gh = h0 - 2 + r;
        bool ok = (unsigned)gh < (unsigned)HH;
        float4 v = {0.f, 0.f, 0.f, 0.f};
        if (ok) v = *(const float4*)(xb + (size_t)(c0 + c) * HW + gh * WW + q * 4);
        *(float4*)&xs[c][r][q * 4] = v;
    }
}

__global__ __launch_bounds__(NT, 3) void dsc_tiled(
    const float* __restrict__ x,
    const float* __restrict__ cen_t,   // [32,3,3]
    const float* __restrict__ dir_t,   // [24,5]
    const float* __restrict__ c2c,     // [32,32]
    const float* __restrict__ p2c,     // [32,24]
    const float* __restrict__ d2c,     // [32,24]
    const float* __restrict__ c2d,     // [24,32]
    const float* __restrict__ d2dW,    // [24,24]
    float* __restrict__ out)
{
    __shared__ float xs[DIR_IN][RH][RW];  // 24*12*52*4 = 59904 B

    const int tid = threadIdx.x;
    const int w  = tid % WW;
    const int hl = tid / WW;                 // 0..7
    const int b  = blockIdx.x / (HH / TH);
    const int h0 = (blockIdx.x % (HH / TH)) * TH;
    const int h  = h0 + hl;
    const float* __restrict__ xb = x   + (size_t)b * C_IN  * HW;
    float* __restrict__       ob = out + (size_t)b * C_OUT * HW;
    const int pix = h * WW + w;

    // 5-tap w offsets; invalid taps point at the zero column (48).
    int woff[5];
#pragma unroll
    for (int i = 0; i < 5; ++i) {
        int ww2 = w + i - 2;
        woff[i] = ((unsigned)ww2 < (unsigned)WW) ? ww2 : 48;
    }

    float cen_acc[CEN_OUT], od[DIR_OUT];
    float yc[16], yt[DIR_IN];

    // ---------- cen half 0 ----------
    stage_group<16>(xs, xb, 0, h0, tid);
    __syncthreads();
#pragma unroll
    for (int c = 0; c < 16; ++c) {
        float a = 0.f;
#pragma unroll
        for (int i = 0; i < 3; ++i)
#pragma unroll
            for (int j = 0; j < 3; ++j)
                a += cen_t[c * 9 + i * 3 + j] * xs[c][hl + 1 + i][woff[j + 1]];
        yc[c] = a;
    }
    __syncthreads();

    // ---------- cen half 1 (stage) + fold half 0 ----------
    stage_group<16>(xs, xb, 16, h0, tid);
#pragma unroll
    for (int o = 0; o < CEN_OUT; ++o) {
        float a = 0.f;
#pragma unroll
        for (int c = 0; c < 16; ++c) a += c2c[o * CEN_IN + c] * yc[c];
        cen_acc[o] = a;
    }
#pragma unroll
    for (int o = 0; o < DIR_OUT; ++o) {
        float a = 0.f;
#pragma unroll
        for (int c = 0; c < 16; ++c) a += c2d[o * CEN_IN + c] * yc[c];
        od[o] = a;
    }
    __syncthreads();
#pragma unroll
    for (int c = 0; c < 16; ++c) {
        float a = 0.f;
#pragma unroll
        for (int i = 0; i < 3; ++i)
#pragma unroll
            for (int j = 0; j < 3; ++j)
                a += cen_t[(16 + c) * 9 + i * 3 + j] * xs[c][hl + 1 + i][woff[j + 1]];
        yc[c] = a;
    }
    __syncthreads();

    // ---------- h group (stage) + fold cen half 1 ----------
    stage_group<24>(xs, xb, 32, h0, tid);
#pragma unroll
    for (int o = 0; o < CEN_OUT; ++o) {
        float a = cen_acc[o];
#pragma unroll
        for (int c = 0; c < 16; ++c) a += c2c[o * CEN_IN + 16 + c] * yc[c];
        cen_acc[o] = a;
    }
#pragma unroll
    for (int o = 0; o < DIR_OUT; ++o) {
        float a = od[o];
#pragma unroll
        for (int c = 0; c < 16; ++c) a += c2d[o * CEN_IN + 16 + c] * yc[c];
        od[o] = a;
    }
    __syncthreads();
    // conv h: row hl+2, cols woff[i]
#pragma unroll
    for (int c = 0; c < DIR_IN; ++c) {
        float a = 0.f;
#pragma unroll
        for (int i = 0; i < 5; ++i)
            a += dir_t[c * 5 + i] * xs[c][hl + 2][woff[i]];
        yt[c] = a;
    }
    __syncthreads();

    // ---------- v group (stage) + fold h ----------
    stage_group<24>(xs, xb, 56, h0, tid);
#pragma unroll
    for (int o = 0; o < CEN_OUT; ++o) {
        float a = cen_acc[o];
#pragma unroll
        for (int c = 0; c < DIR_IN; ++c) a += p2c[o * DIR_IN + c] * yt[c];
        cen_acc[o] = a;
    }
#pragma unroll
    for (int o = 0; o < DIR_OUT; ++o) {
        float a = od[o];
#pragma unroll
        for (int c = 0; c < DIR_IN; ++c) a += d2dW[o * DIR_IN + c] * yt[c];
        ob[(size_t)(CEN_OUT + 0 * DIR_OUT + o) * HW + pix] = a;
    }
    __syncthreads();
    // conv v: rows hl+i, col w
#pragma unroll
    for (int c = 0; c < DIR_IN; ++c) {
        float a = 0.f;
#pragma unroll
        for (int i = 0; i < 5; ++i)
            a += dir_t[c * 5 + i] * xs[c][hl + i][w];
        yt[c] = a;
    }
    __syncthreads();

    // ---------- d1 group (stage) + fold v ----------
    stage_group<24>(xs, xb, 80, h0, tid);
#pragma unroll
    for (int o = 0; o < CEN_OUT; ++o) {
        float a = cen_acc[o];
#pragma unroll
        for (int c = 0; c < DIR_IN; ++c) a += p2c[o * DIR_IN + c] * yt[c];
        cen_acc[o] = a;
    }
#pragma unroll
    for (int o = 0; o < DIR_OUT; ++o) {
        float a = od[o];
#pragma unroll
        for (int c = 0; c < DIR_IN; ++c) a += d2dW[o * DIR_IN + c] * yt[c];
        ob[(size_t)(CEN_OUT + 1 * DIR_OUT + o) * HW + pix] = a;
    }
    __syncthreads();
    // conv d1: rows hl+i, cols woff[i]
#pragma unroll
    for (int c = 0; c < DIR_IN; ++c) {
        float a = 0.f;
#pragma unroll
        for (int i = 0; i < 5; ++i)
            a += dir_t[c * 5 + i] * xs[c][hl + i][woff[i]];
        yt[c] = a;
    }
    __syncthreads();

    // ---------- d2 group (stage) + fold d1 ----------
    stage_group<24>(xs, xb, 104, h0, tid);
#pragma unroll
    for (int o = 0; o < CEN_OUT; ++o) {
        float a = cen_acc[o];
#pragma unroll
        for (int c = 0; c < DIR_IN; ++c) a += d2c[o * DIR_IN + c] * yt[c];
        cen_acc[o] = a;
    }
#pragma unroll
    for (int o = 0; o < DIR_OUT; ++o) {
        float a = od[o];
#pragma unroll
        for (int c = 0; c < DIR_IN; ++c) a += d2dW[o * DIR_IN + c] * yt[c];
        ob[(size_t)(CEN_OUT + 2 * DIR_OUT + o) * HW + pix] = a;
    }
    __syncthreads();
    // conv d2: rows hl+i, cols woff[4-i]
#pragma unroll
    for (int c = 0; c < DIR_IN; ++c) {
        float a = 0.f;
#pragma unroll
        for (int i = 0; i < 5; ++i)
            a += dir_t[c * 5 + i] * xs[c][hl + i][woff[4 - i]];
        yt[c] = a;
    }

    // ---------- final folds + writes ----------
#pragma unroll
    for (int o = 0; o < CEN_OUT; ++o) {
        float a = cen_acc[o];
#pragma unroll
        for (int c = 0; c < DIR_IN; ++c) a += d2c[o * DIR_IN + c] * yt[c];
        ob[(size_t)o * HW + pix] = a;
    }
#pragma unroll
    for (int o = 0; o < DIR_OUT; ++o) {
        float a = od[o];
#pragma unroll
        for (int c = 0; c < DIR_IN; ++c) a += d2dW[o * DIR_IN + c] * yt[c];
        ob[(size_t)(CEN_OUT + 3 * DIR_OUT + o) * HW + pix] = a;
    }
}

extern "C" void kernel_launch(void* const* d_in, const int* in_sizes, int n_in,
                              void* d_out, int out_size, void* d_ws, size_t ws_size,
                              hipStream_t stream) {
    const float* x     = (const float*)d_in[0];
    const float* cen_t = (const float*)d_in[1];
    const float* dir_t = (const float*)d_in[2];
    const float* c2c   = (const float*)d_in[3];
    const float* p2c   = (const float*)d_in[4];
    const float* d2c   = (const float*)d_in[5];
    const float* c2d   = (const float*)d_in[6];
    const float* d2dW  = (const float*)d_in[7];
    float* out = (float*)d_out;

    const int blocks = 128 * (HH / TH);   // 768
    dsc_tiled<<<blocks, NT, 0, stream>>>(x, cen_t, dir_t, c2c, p2c, d2c, c2d, d2dW, out);
}

// Round 3
// 791.822 us; speedup vs baseline: 1.1227x; 1.1227x over previous
//
#include <hip/hip_runtime.h>

// DirectionalSeparableConv2D — LDS-tiled fused kernel (round 3).
// Round-2 regression root cause: __launch_bounds__(384,3) clamped the
// allocator to 84 VGPR -> ~1 GB of scratch spill traffic (WRITE_SIZE 902 MB
// vs 147 MB of real output). Fix: unconstrained launch bounds; occupancy is
// LDS-limited to 2 blocks/CU anyway.
//
// x: (128,128,48,48) f32 NCHW. out: (128,128,48,48) f32.
// in ch: [0,32)=cen, [32,56)=h, [56,80)=v, [80,104)=d1, [104,128)=d2
// Block = 384 threads = (b, 8 rows x 48 cols) tile, 1 pixel/thread.

namespace {
constexpr int HH = 48, WW = 48;
constexpr int CEN_IN = 32, DIR_IN = 24, CEN_OUT = 32, DIR_OUT = 24;
constexpr int C_IN = 128, C_OUT = 128, HW = HH * WW;
constexpr int TH = 8;            // output rows per block
constexpr int RH = TH + 4;       // staged rows incl. halo (12)
constexpr int RW = 52;           // LDS row stride (dwords); col 48 = zero column
constexpr int NT = TH * WW;      // 384 threads
}

template <int C>
__device__ __forceinline__ void stage_group(float (*__restrict__ xs)[RH][RW],
                                            const float* __restrict__ xb,
                                            int c0, int h0, int tid) {
    if (tid < C * RH) {
        int c = tid / RH, r = tid % RH;
        *(float4*)&xs[c][r][48] = float4{0.f, 0.f, 0.f, 0.f};
    }
    constexpr int ITEMS = C * RH * 12;   // float4 quads of real data
    constexpr int PT = ITEMS / NT;       // 6 (C=16) or 9 (C=24), exact
#pragma unroll
    for (int k = 0; k < PT; ++k) {
        int i = tid + k * NT;
        int q = i % 12;
        int rc = i / 12;
        int r = rc % RH;
        int c = rc / RH;
        int gh = h0 - 2 + r;
        bool ok = (unsigned)gh < (unsigned)HH;
        float4 v = {0.f, 0.f, 0.f, 0.f};
        if (ok) v = *(const float4*)(xb + (size_t)(c0 + c) * HW + gh * WW + q * 4);
        *(float4*)&xs[c][r][q * 4] = v;
    }
}

__global__ __launch_bounds__(NT) void dsc_tiled(
    const float* __restrict__ x,
    const float* __restrict__ cen_t,   // [32,3,3]
    const float* __restrict__ dir_t,   // [24,5]
    const float* __restrict__ c2c,     // [32,32]
    const float* __restrict__ p2c,     // [32,24]
    const float* __restrict__ d2c,     // [32,24]
    const float* __restrict__ c2d,     // [24,32]
    const float* __restrict__ d2dW,    // [24,24]
    float* __restrict__ out)
{
    __shared__ float xs[DIR_IN][RH][RW];  // 24*12*52*4 = 59904 B

    const int tid = threadIdx.x;
    const int w  = tid % WW;
    const int hl = tid / WW;                 // 0..7
    const int b  = blockIdx.x / (HH / TH);
    const int h0 = (blockIdx.x % (HH / TH)) * TH;
    const int h  = h0 + hl;
    const float* __restrict__ xb = x   + (size_t)b * C_IN  * HW;
    float* __restrict__       ob = out + (size_t)b * C_OUT * HW;
    const int pix = h * WW + w;

    int woff[5];
#pragma unroll
    for (int i = 0; i < 5; ++i) {
        int ww2 = w + i - 2;
        woff[i] = ((unsigned)ww2 < (unsigned)WW) ? ww2 : 48;
    }

    float cen_acc[CEN_OUT], od[DIR_OUT];
    float yc[16], yt[DIR_IN];

    // ---------- cen half 0 ----------
    stage_group<16>(xs, xb, 0, h0, tid);
    __syncthreads();
#pragma unroll
    for (int c = 0; c < 16; ++c) {
        float a = 0.f;
#pragma unroll
        for (int i = 0; i < 3; ++i)
#pragma unroll
            for (int j = 0; j < 3; ++j)
                a += cen_t[c * 9 + i * 3 + j] * xs[c][hl + 1 + i][woff[j + 1]];
        yc[c] = a;
    }
    __syncthreads();

    // ---------- cen half 1 (stage) + fold half 0 ----------
    stage_group<16>(xs, xb, 16, h0, tid);
#pragma unroll
    for (int o = 0; o < CEN_OUT; ++o) {
        float a = 0.f;
#pragma unroll
        for (int c = 0; c < 16; ++c) a += c2c[o * CEN_IN + c] * yc[c];
        cen_acc[o] = a;
    }
#pragma unroll
    for (int o = 0; o < DIR_OUT; ++o) {
        float a = 0.f;
#pragma unroll
        for (int c = 0; c < 16; ++c) a += c2d[o * CEN_IN + c] * yc[c];
        od[o] = a;
    }
    __syncthreads();
#pragma unroll
    for (int c = 0; c < 16; ++c) {
        float a = 0.f;
#pragma unroll
        for (int i = 0; i < 3; ++i)
#pragma unroll
            for (int j = 0; j < 3; ++j)
                a += cen_t[(16 + c) * 9 + i * 3 + j] * xs[c][hl + 1 + i][woff[j + 1]];
        yc[c] = a;
    }
    __syncthreads();

    // ---------- h group (stage) + fold cen half 1 ----------
    stage_group<24>(xs, xb, 32, h0, tid);
#pragma unroll
    for (int o = 0; o < CEN_OUT; ++o) {
        float a = cen_acc[o];
#pragma unroll
        for (int c = 0; c < 16; ++c) a += c2c[o * CEN_IN + 16 + c] * yc[c];
        cen_acc[o] = a;
    }
#pragma unroll
    for (int o = 0; o < DIR_OUT; ++o) {
        float a = od[o];
#pragma unroll
        for (int c = 0; c < 16; ++c) a += c2d[o * CEN_IN + 16 + c] * yc[c];
        od[o] = a;
    }
    __syncthreads();
#pragma unroll
    for (int c = 0; c < DIR_IN; ++c) {
        float a = 0.f;
#pragma unroll
        for (int i = 0; i < 5; ++i)
            a += dir_t[c * 5 + i] * xs[c][hl + 2][woff[i]];
        yt[c] = a;
    }
    __syncthreads();

    // ---------- v group (stage) + fold h ----------
    stage_group<24>(xs, xb, 56, h0, tid);
#pragma unroll
    for (int o = 0; o < CEN_OUT; ++o) {
        float a = cen_acc[o];
#pragma unroll
        for (int c = 0; c < DIR_IN; ++c) a += p2c[o * DIR_IN + c] * yt[c];
        cen_acc[o] = a;
    }
#pragma unroll
    for (int o = 0; o < DIR_OUT; ++o) {
        float a = od[o];
#pragma unroll
        for (int c = 0; c < DIR_IN; ++c) a += d2dW[o * DIR_IN + c] * yt[c];
        ob[(size_t)(CEN_OUT + 0 * DIR_OUT + o) * HW + pix] = a;
    }
    __syncthreads();
#pragma unroll
    for (int c = 0; c < DIR_IN; ++c) {
        float a = 0.f;
#pragma unroll
        for (int i = 0; i < 5; ++i)
            a += dir_t[c * 5 + i] * xs[c][hl + i][w];
        yt[c] = a;
    }
    __syncthreads();

    // ---------- d1 group (stage) + fold v ----------
    stage_group<24>(xs, xb, 80, h0, tid);
#pragma unroll
    for (int o = 0; o < CEN_OUT; ++o) {
        float a = cen_acc[o];
#pragma unroll
        for (int c = 0; c < DIR_IN; ++c) a += p2c[o * DIR_IN + c] * yt[c];
        cen_acc[o] = a;
    }
#pragma unroll
    for (int o = 0; o < DIR_OUT; ++o) {
        float a = od[o];
#pragma unroll
        for (int c = 0; c < DIR_IN; ++c) a += d2dW[o * DIR_IN + c] * yt[c];
        ob[(size_t)(CEN_OUT + 1 * DIR_OUT + o) * HW + pix] = a;
    }
    __syncthreads();
#pragma unroll
    for (int c = 0; c < DIR_IN; ++c) {
        float a = 0.f;
#pragma unroll
        for (int i = 0; i < 5; ++i)
            a += dir_t[c * 5 + i] * xs[c][hl + i][woff[i]];
        yt[c] = a;
    }
    __syncthreads();

    // ---------- d2 group (stage) + fold d1 ----------
    stage_group<24>(xs, xb, 104, h0, tid);
#pragma unroll
    for (int o = 0; o < CEN_OUT; ++o) {
        float a = cen_acc[o];
#pragma unroll
        for (int c = 0; c < DIR_IN; ++c) a += d2c[o * DIR_IN + c] * yt[c];
        cen_acc[o] = a;
    }
#pragma unroll
    for (int o = 0; o < DIR_OUT; ++o) {
        float a = od[o];
#pragma unroll
        for (int c = 0; c < DIR_IN; ++c) a += d2dW[o * DIR_IN + c] * yt[c];
        ob[(size_t)(CEN_OUT + 2 * DIR_OUT + o) * HW + pix] = a;
    }
    __syncthreads();
#pragma unroll
    for (int c = 0; c < DIR_IN; ++c) {
        float a = 0.f;
#pragma unroll
        for (int i = 0; i < 5; ++i)
            a += dir_t[c * 5 + i] * xs[c][hl + i][woff[4 - i]];
        yt[c] = a;
    }

    // ---------- final folds + writes ----------
#pragma unroll
    for (int o = 0; o < CEN_OUT; ++o) {
        float a = cen_acc[o];
#pragma unroll
        for (int c = 0; c < DIR_IN; ++c) a += d2c[o * DIR_IN + c] * yt[c];
        ob[(size_t)o * HW + pix] = a;
    }
#pragma unroll
    for (int o = 0; o < DIR_OUT; ++o) {
        float a = od[o];
#pragma unroll
        for (int c = 0; c < DIR_IN; ++c) a += d2dW[o * DIR_IN + c] * yt[c];
        ob[(size_t)(CEN_OUT + 3 * DIR_OUT + o) * HW + pix] = a;
    }
}

extern "C" void kernel_launch(void* const* d_in, const int* in_sizes, int n_in,
                              void* d_out, int out_size, void* d_ws, size_t ws_size,
                              hipStream_t stream) {
    const float* x     = (const float*)d_in[0];
    const float* cen_t = (const float*)d_in[1];
    const float* dir_t = (const float*)d_in[2];
    const float* c2c   = (const float*)d_in[3];
    const float* p2c   = (const float*)d_in[4];
    const float* d2c   = (const float*)d_in[5];
    const float* c2d   = (const float*)d_in[6];
    const float* d2dW  = (const float*)d_in[7];
    float* out = (float*)d_out;

    const int blocks = 128 * (HH / TH);   // 768
    dsc_tiled<<<blocks, NT, 0, stream>>>(x, cen_t, dir_t, c2c, p2c, d2c, c2d, d2dW, out);
}

// Round 4
// 735.437 us; speedup vs baseline: 1.2087x; 1.0767x over previous
//
#include <hip/hip_runtime.h>

// DirectionalSeparableConv2D — LDS-tiled, async-staged (round 4).
// Round-3 root cause: staged float4 data held in VGPRs across folds ->
// allocator capped at 128 and spilled (~535 MB scratch writes). Fix: stage
// via __builtin_amdgcn_global_load_lds (no data VGPRs). LDS tile is
// [C][12][64] floats so the staging index is byte-linear (wave-uniform base +
// lane*16 requirement). Halo rows / cols 48..63 are loaded from a 16 B zero
// block in d_ws -> no boundary masks anywhere.
//
// x: (128,128,48,48) f32 NCHW. out: (128,128,48,48) f32.
// in ch: [0,32)=cen, [32,56)=h, [56,80)=v, [80,104)=d1, [104,128)=d2
// Block = 384 threads = (b, 8 rows x 48 cols), 1 pixel/thread.

namespace {
constexpr int HH = 48, WW = 48;
constexpr int CEN_IN = 32, DIR_IN = 24, CEN_OUT = 32, DIR_OUT = 24;
constexpr int C_IN = 128, C_OUT = 128, HW = HH * WW;
constexpr int TH = 8;            // output rows per block
constexpr int RH = TH + 4;       // staged rows incl. halo (12)
constexpr int RW = 64;           // LDS row stride (floats); cols 48..63 = zeros
constexpr int QPR = RW / 4;      // 16 quads per row
constexpr int NT = TH * WW;      // 384 threads
}

__device__ __forceinline__ void gl_lds16(const float* g, float* l) {
    __builtin_amdgcn_global_load_lds(
        (const __attribute__((address_space(1))) unsigned int*)g,
        (__attribute__((address_space(3))) unsigned int*)l,
        16, 0, 0);
}

// Stage C channels [c0,c0+C) into xs (flat view), rows h0-2..h0+9.
// Invalid rows and the 16-col pad read from the 16B zero block zb.
template <int C>
__device__ __forceinline__ void stage_group(float* __restrict__ xsf,
                                            const float* __restrict__ xb,
                                            const float* __restrict__ zb,
                                            int c0, int h0, int tid) {
    constexpr int ITEMS = C * RH * QPR;   // C=16: 3072, C=24: 4608
    constexpr int PT = ITEMS / NT;        // 8 or 12, exact
#pragma unroll
    for (int k = 0; k < PT; ++k) {
        int i = tid + k * NT;
        int q = i & (QPR - 1);
        int rc = i >> 4;
        int r = rc % RH;
        int c = rc / RH;
        int gh = h0 - 2 + r;
        bool ok = ((unsigned)gh < (unsigned)HH) & (q < 12);
        const float* src = ok ? (xb + (size_t)(c0 + c) * HW + gh * WW + q * 4) : zb;
        gl_lds16(src, xsf + (size_t)i * 4);
    }
}

__global__ __launch_bounds__(NT) void dsc_tiled(
    const float* __restrict__ x,
    const float* __restrict__ cen_t,   // [32,3,3]
    const float* __restrict__ dir_t,   // [24,5]
    const float* __restrict__ c2c,     // [32,32]
    const float* __restrict__ p2c,     // [32,24]
    const float* __restrict__ d2c,     // [32,24]
    const float* __restrict__ c2d,     // [24,32]
    const float* __restrict__ d2dW,    // [24,24]
    const float* __restrict__ zb,      // 16B zero block (d_ws)
    float* __restrict__ out)
{
    __shared__ float xs[DIR_IN][RH][RW];  // 24*12*64*4 = 73728 B
    float* xsf = &xs[0][0][0];

    const int tid = threadIdx.x;
    const int w  = tid % WW;
    const int hl = tid / WW;                 // 0..7
    const int b  = blockIdx.x / (HH / TH);
    const int h0 = (blockIdx.x % (HH / TH)) * TH;
    const int h  = h0 + hl;
    const float* __restrict__ xb = x   + (size_t)b * C_IN  * HW;
    float* __restrict__       ob = out + (size_t)b * C_OUT * HW;
    const int pix = h * WW + w;

    // 5-tap w offsets; invalid taps -> col 48 (zero region).
    int woff[5];
#pragma unroll
    for (int i = 0; i < 5; ++i) {
        int ww2 = w + i - 2;
        woff[i] = ((unsigned)ww2 < (unsigned)WW) ? ww2 : 48;
    }

    float cen_acc[CEN_OUT], od[DIR_OUT];
    float yc[16], yt[DIR_IN];

    // ---------- cen half 0 ----------
    stage_group<16>(xsf, xb, zb, 0, h0, tid);
    __syncthreads();
#pragma unroll
    for (int c = 0; c < 16; ++c) {
        float a = 0.f;
#pragma unroll
        for (int i = 0; i < 3; ++i)
#pragma unroll
            for (int j = 0; j < 3; ++j)
                a += cen_t[c * 9 + i * 3 + j] * xs[c][hl + 1 + i][woff[j + 1]];
        yc[c] = a;
    }
    __syncthreads();

    // ---------- stage cen half 1 + fold half 0 ----------
    stage_group<16>(xsf, xb, zb, 16, h0, tid);
#pragma unroll
    for (int o = 0; o < CEN_OUT; ++o) {
        float a = 0.f;
#pragma unroll
        for (int c = 0; c < 16; ++c) a += c2c[o * CEN_IN + c] * yc[c];
        cen_acc[o] = a;
    }
#pragma unroll
    for (int o = 0; o < DIR_OUT; ++o) {
        float a = 0.f;
#pragma unroll
        for (int c = 0; c < 16; ++c) a += c2d[o * CEN_IN + c] * yc[c];
        od[o] = a;
    }
    __syncthreads();
#pragma unroll
    for (int c = 0; c < 16; ++c) {
        float a = 0.f;
#pragma unroll
        for (int i = 0; i < 3; ++i)
#pragma unroll
            for (int j = 0; j < 3; ++j)
                a += cen_t[(16 + c) * 9 + i * 3 + j] * xs[c][hl + 1 + i][woff[j + 1]];
        yc[c] = a;
    }
    __syncthreads();

    // ---------- stage h + fold cen half 1 ----------
    stage_group<24>(xsf, xb, zb, 32, h0, tid);
#pragma unroll
    for (int o = 0; o < CEN_OUT; ++o) {
        float a = cen_acc[o];
#pragma unroll
        for (int c = 0; c < 16; ++c) a += c2c[o * CEN_IN + 16 + c] * yc[c];
        cen_acc[o] = a;
    }
#pragma unroll
    for (int o = 0; o < DIR_OUT; ++o) {
        float a = od[o];
#pragma unroll
        for (int c = 0; c < 16; ++c) a += c2d[o * CEN_IN + 16 + c] * yc[c];
        od[o] = a;
    }
    __syncthreads();
#pragma unroll
    for (int c = 0; c < DIR_IN; ++c) {
        float a = 0.f;
#pragma unroll
        for (int i = 0; i < 5; ++i)
            a += dir_t[c * 5 + i] * xs[c][hl + 2][woff[i]];
        yt[c] = a;
    }
    __syncthreads();

    // ---------- stage v + fold h ----------
    stage_group<24>(xsf, xb, zb, 56, h0, tid);
#pragma unroll
    for (int o = 0; o < CEN_OUT; ++o) {
        float a = cen_acc[o];
#pragma unroll
        for (int c = 0; c < DIR_IN; ++c) a += p2c[o * DIR_IN + c] * yt[c];
        cen_acc[o] = a;
    }
#pragma unroll
    for (int o = 0; o < DIR_OUT; ++o) {
        float a = od[o];
#pragma unroll
        for (int c = 0; c < DIR_IN; ++c) a += d2dW[o * DIR_IN + c] * yt[c];
        ob[(size_t)(CEN_OUT + 0 * DIR_OUT + o) * HW + pix] = a;
    }
    __syncthreads();
#pragma unroll
    for (int c = 0; c < DIR_IN; ++c) {
        float a = 0.f;
#pragma unroll
        for (int i = 0; i < 5; ++i)
            a += dir_t[c * 5 + i] * xs[c][hl + i][w];
        yt[c] = a;
    }
    __syncthreads();

    // ---------- stage d1 + fold v ----------
    stage_group<24>(xsf, xb, zb, 80, h0, tid);
#pragma unroll
    for (int o = 0; o < CEN_OUT; ++o) {
        float a = cen_acc[o];
#pragma unroll
        for (int c = 0; c < DIR_IN; ++c) a += p2c[o * DIR_IN + c] * yt[c];
        cen_acc[o] = a;
    }
#pragma unroll
    for (int o = 0; o < DIR_OUT; ++o) {
        float a = od[o];
#pragma unroll
        for (int c = 0; c < DIR_IN; ++c) a += d2dW[o * DIR_IN + c] * yt[c];
        ob[(size_t)(CEN_OUT + 1 * DIR_OUT + o) * HW + pix] = a;
    }
    __syncthreads();
#pragma unroll
    for (int c = 0; c < DIR_IN; ++c) {
        float a = 0.f;
#pragma unroll
        for (int i = 0; i < 5; ++i)
            a += dir_t[c * 5 + i] * xs[c][hl + i][woff[i]];
        yt[c] = a;
    }
    __syncthreads();

    // ---------- stage d2 + fold d1 ----------
    stage_group<24>(xsf, xb, zb, 104, h0, tid);
#pragma unroll
    for (int o = 0; o < CEN_OUT; ++o) {
        float a = cen_acc[o];
#pragma unroll
        for (int c = 0; c < DIR_IN; ++c) a += d2c[o * DIR_IN + c] * yt[c];
        cen_acc[o] = a;
    }
#pragma unroll
    for (int o = 0; o < DIR_OUT; ++o) {
        float a = od[o];
#pragma unroll
        for (int c = 0; c < DIR_IN; ++c) a += d2dW[o * DIR_IN + c] * yt[c];
        ob[(size_t)(CEN_OUT + 2 * DIR_OUT + o) * HW + pix] = a;
    }
    __syncthreads();
#pragma unroll
    for (int c = 0; c < DIR_IN; ++c) {
        float a = 0.f;
#pragma unroll
        for (int i = 0; i < 5; ++i)
            a += dir_t[c * 5 + i] * xs[c][hl + i][woff[4 - i]];
        yt[c] = a;
    }

    // ---------- final folds + writes ----------
#pragma unroll
    for (int o = 0; o < CEN_OUT; ++o) {
        float a = cen_acc[o];
#pragma unroll
        for (int c = 0; c < DIR_IN; ++c) a += d2c[o * DIR_IN + c] * yt[c];
        ob[(size_t)o * HW + pix] = a;
    }
#pragma unroll
    for (int o = 0; o < DIR_OUT; ++o) {
        float a = od[o];
#pragma unroll
        for (int c = 0; c < DIR_IN; ++c) a += d2dW[o * DIR_IN + c] * yt[c];
        ob[(size_t)(CEN_OUT + 3 * DIR_OUT + o) * HW + pix] = a;
    }
}

extern "C" void kernel_launch(void* const* d_in, const int* in_sizes, int n_in,
                              void* d_out, int out_size, void* d_ws, size_t ws_size,
                              hipStream_t stream) {
    const float* x     = (const float*)d_in[0];
    const float* cen_t = (const float*)d_in[1];
    const float* dir_t = (const float*)d_in[2];
    const float* c2c   = (const float*)d_in[3];
    const float* p2c   = (const float*)d_in[4];
    const float* d2c   = (const float*)d_in[5];
    const float* c2d   = (const float*)d_in[6];
    const float* d2dW  = (const float*)d_in[7];
    float* out = (float*)d_out;
    float* zb  = (float*)d_ws;            // 16B zero block

    hipMemsetAsync(zb, 0, 64, stream);    // harness poisons ws; re-zero every call

    const int blocks = 128 * (HH / TH);   // 768
    dsc_tiled<<<blocks, NT, 0, stream>>>(x, cen_t, dir_t, c2c, p2c, d2c, c2d, d2dW, zb, out);
}

// Round 5
// 732.499 us; speedup vs baseline: 1.2136x; 1.0040x over previous
//
#include <hip/hip_runtime.h>

// DirectionalSeparableConv2D — round 5: kill register spills structurally.
// r2-r4 all spilled (WRITE_SIZE 902/682/607 MB vs 147 MB real output): the
// persistent accumulator state (96 floats) + headroom exceeds the 128-VGPR
// occupancy step hipcc targets for 384-thread blocks. This round:
//   * od[24] lives in LDS (written once after cen phase, read at each dir
//     group start) -> -24 regs
//   * convs processed in <=12-channel chunks (cen 12+12+8, dirs 12+12)
//     -> y[] is 12 regs, xs LDS tile is [12][12][64]
// Steady live state ~68 floats -> ~90 VGPR, no spills, 2 blocks/CU.
// Staging stays on __builtin_amdgcn_global_load_lds (16B, zero data regs);
// halo rows + cols 48..63 load from a 16B zero block in d_ws (no masks).

namespace {
constexpr int HH = 48, WW = 48;
constexpr int CEN_OUT = 32, DIR_OUT = 24;
constexpr int C_IN = 128, C_OUT = 128, HW = HH * WW;
constexpr int TH = 8;            // output rows per block
constexpr int RH = TH + 4;       // staged rows incl. halo (12)
constexpr int RW = 64;           // LDS row stride (floats); cols 48..63 zero
constexpr int QPR = RW / 4;      // 16 quads per row
constexpr int NT = TH * WW;      // 384 threads
}

__device__ __forceinline__ void gl_lds16(const float* g, float* l) {
    __builtin_amdgcn_global_load_lds(
        (const __attribute__((address_space(1))) unsigned int*)g,
        (__attribute__((address_space(3))) unsigned int*)l,
        16, 0, 0);
}

// Stage C channels [c0,c0+C) into xsf, rows h0-2..h0+9. Halo rows and the
// 16-col pad read from the 16B zero block zb.
template <int C>
__device__ __forceinline__ void stage(float* __restrict__ xsf,
                                      const float* __restrict__ xb,
                                      const float* __restrict__ zb,
                                      int c0, int h0, int tid) {
    constexpr int ITEMS = C * RH * QPR;
    constexpr int PT = ITEMS / NT;          // 12ch: 6, 8ch: 4 (exact)
    static_assert(ITEMS % NT == 0, "stage divisibility");
#pragma unroll
    for (int k = 0; k < PT; ++k) {
        int i = tid + k * NT;
        int q = i & (QPR - 1);
        int rc = i >> 4;
        int r = rc % RH;
        int c = rc / RH;
        int gh = h0 - 2 + r;
        bool ok = ((unsigned)gh < (unsigned)HH) && (q < 12);
        const float* src = ok ? (xb + (size_t)(c0 + c) * HW + gh * WW + q * 4) : zb;
        gl_lds16(src, xsf + (size_t)i * 4);
    }
}

// ---- conv macros: fill y[0..N) from xs chunk; weight channel base CB ----
#define CONV3(N, CB)                                                          \
    do {                                                                      \
        _Pragma("unroll") for (int c = 0; c < (N); ++c) {                     \
            float a = 0.f;                                                    \
            _Pragma("unroll") for (int i = 0; i < 3; ++i)                     \
                _Pragma("unroll") for (int j = 0; j < 3; ++j)                 \
                    a += cen_t[((CB) + c) * 9 + i * 3 + j] *                  \
                         xs[c][hl + 1 + i][woff[j + 1]];                      \
            y[c] = a;                                                         \
        }                                                                     \
    } while (0)

#define CONVDIR(CB, ROW, COL)                                                 \
    do {                                                                      \
        _Pragma("unroll") for (int c = 0; c < 12; ++c) {                      \
            float a = 0.f;                                                    \
            _Pragma("unroll") for (int i = 0; i < 5; ++i)                     \
                a += dir_t[((CB) + c) * 5 + i] * xs[c][ROW][COL];             \
            y[c] = a;                                                         \
        }                                                                     \
    } while (0)

// ---- fold macros ----
#define FOLD_CEN(CB, N)                                                       \
    do {                                                                      \
        _Pragma("unroll") for (int o = 0; o < CEN_OUT; ++o) {                 \
            float a = cen_acc[o];                                             \
            _Pragma("unroll") for (int c = 0; c < (N); ++c)                   \
                a += c2c[o * 32 + (CB) + c] * y[c];                           \
            cen_acc[o] = a;                                                   \
        }                                                                     \
        _Pragma("unroll") for (int o = 0; o < DIR_OUT; ++o) {                 \
            float a = od[o];                                                  \
            _Pragma("unroll") for (int c = 0; c < (N); ++c)                   \
                a += c2d[o * 32 + (CB) + c] * y[c];                           \
            od[o] = a;                                                        \
        }                                                                     \
    } while (0)

#define FOLD_DIR0(W2C)                                                        \
    do {                                                                      \
        _Pragma("unroll") for (int o = 0; o < CEN_OUT; ++o) {                 \
            float a = cen_acc[o];                                             \
            _Pragma("unroll") for (int c = 0; c < 12; ++c)                    \
                a += (W2C)[o * 24 + c] * y[c];                                \
            cen_acc[o] = a;                                                   \
        }                                                                     \
        _Pragma("unroll") for (int o = 0; o < DIR_OUT; ++o) {                 \
            float a = odl[o][tid];                                            \
            _Pragma("unroll") for (int c = 0; c < 12; ++c)                    \
                a += d2dW[o * 24 + c] * y[c];                                 \
            da[o] = a;                                                        \
        }                                                                     \
    } while (0)

#define FOLD_DIR1(W2C, G)                                                     \
    do {                                                                      \
        _Pragma("unroll") for (int o = 0; o < CEN_OUT; ++o) {                 \
            float a = cen_acc[o];                                             \
            _Pragma("unroll") for (int c = 0; c < 12; ++c)                    \
                a += (W2C)[o * 24 + 12 + c] * y[c];                           \
            cen_acc[o] = a;                                                   \
        }                                                                     \
        _Pragma("unroll") for (int o = 0; o < DIR_OUT; ++o) {                 \
            float a = da[o];                                                  \
            _Pragma("unroll") for (int c = 0; c < 12; ++c)                    \
                a += d2dW[o * 24 + 12 + c] * y[c];                            \
            ob[(size_t)(CEN_OUT + (G) * DIR_OUT + o) * HW + pix] = a;         \
        }                                                                     \
    } while (0)

__global__ __launch_bounds__(NT) void dsc5(
    const float* __restrict__ x,
    const float* __restrict__ cen_t,   // [32,3,3]
    const float* __restrict__ dir_t,   // [24,5]
    const float* __restrict__ c2c,     // [32,32]
    const float* __restrict__ p2c,     // [32,24]
    const float* __restrict__ d2c,     // [32,24]
    const float* __restrict__ c2d,     // [24,32]
    const float* __restrict__ d2dW,    // [24,24]
    const float* __restrict__ zb,      // 16B zero block (d_ws)
    float* __restrict__ out)
{
    __shared__ float xs[12][RH][RW];        // 36864 B
    __shared__ float odl[DIR_OUT][NT];      // 36864 B  (total 73728)
    float* xsf = &xs[0][0][0];

    const int tid = threadIdx.x;
    const int w  = tid % WW;
    const int hl = tid / WW;                 // 0..7
    const int b  = blockIdx.x / (HH / TH);
    const int h0 = (blockIdx.x % (HH / TH)) * TH;
    const int h  = h0 + hl;
    const float* __restrict__ xb = x   + (size_t)b * C_IN  * HW;
    float* __restrict__       ob = out + (size_t)b * C_OUT * HW;
    const int pix = h * WW + w;

    int woff[5];
#pragma unroll
    for (int i = 0; i < 5; ++i) {
        int ww2 = w + i - 2;
        woff[i] = ((unsigned)ww2 < (unsigned)WW) ? ww2 : 48;
    }

    float cen_acc[CEN_OUT], od[DIR_OUT], da[DIR_OUT], y[12];
#pragma unroll
    for (int o = 0; o < CEN_OUT; ++o) cen_acc[o] = 0.f;
#pragma unroll
    for (int o = 0; o < DIR_OUT; ++o) od[o] = 0.f;

    // ================= cen phase: chunks 12,12,8 =================
    stage<12>(xsf, xb, zb, 0, h0, tid);
    __syncthreads();
    CONV3(12, 0);
    __syncthreads();

    stage<12>(xsf, xb, zb, 12, h0, tid);
    FOLD_CEN(0, 12);
    __syncthreads();
    CONV3(12, 12);
    __syncthreads();

    stage<8>(xsf, xb, zb, 24, h0, tid);
    FOLD_CEN(12, 12);
    __syncthreads();
    CONV3(8, 24);
    __syncthreads();

    // ================= h group (ch 32..55) =================
    stage<12>(xsf, xb, zb, 32, h0, tid);
    FOLD_CEN(24, 8);
#pragma unroll
    for (int o = 0; o < DIR_OUT; ++o) odl[o][tid] = od[o];   // od -> LDS
    __syncthreads();
    CONVDIR(0, hl + 2, woff[i]);
    __syncthreads();

    stage<12>(xsf, xb, zb, 44, h0, tid);
    FOLD_DIR0(p2c);
    __syncthreads();
    CONVDIR(12, hl + 2, woff[i]);
    __syncthreads();

    // ================= v group (ch 56..79) =================
    stage<12>(xsf, xb, zb, 56, h0, tid);
    FOLD_DIR1(p2c, 0);
    __syncthreads();
    CONVDIR(0, hl + i, w);
    __syncthreads();

    stage<12>(xsf, xb, zb, 68, h0, tid);
    FOLD_DIR0(p2c);
    __syncthreads();
    CONVDIR(12, hl + i, w);
    __syncthreads();

    // ================= d1 group (ch 80..103) =================
    stage<12>(xsf, xb, zb, 80, h0, tid);
    FOLD_DIR1(p2c, 1);
    __syncthreads();
    CONVDIR(0, hl + i, woff[i]);
    __syncthreads();

    stage<12>(xsf, xb, zb, 92, h0, tid);
    FOLD_DIR0(d2c);
    __syncthreads();
    CONVDIR(12, hl + i, woff[i]);
    __syncthreads();

    // ================= d2 group (ch 104..127) =================
    stage<12>(xsf, xb, zb, 104, h0, tid);
    FOLD_DIR1(d2c, 2);
    __syncthreads();
    CONVDIR(0, hl + i, woff[4 - i]);
    __syncthreads();

    stage<12>(xsf, xb, zb, 116, h0, tid);
    FOLD_DIR0(d2c);
    __syncthreads();
    CONVDIR(12, hl + i, woff[4 - i]);

    // ================= epilogue =================
    FOLD_DIR1(d2c, 3);
#pragma unroll
    for (int o = 0; o < CEN_OUT; ++o) ob[(size_t)o * HW + pix] = cen_acc[o];
}

extern "C" void kernel_launch(void* const* d_in, const int* in_sizes, int n_in,
                              void* d_out, int out_size, void* d_ws, size_t ws_size,
                              hipStream_t stream) {
    const float* x     = (const float*)d_in[0];
    const float* cen_t = (const float*)d_in[1];
    const float* dir_t = (const float*)d_in[2];
    const float* c2c   = (const float*)d_in[3];
    const float* p2c   = (const float*)d_in[4];
    const float* d2c   = (const float*)d_in[5];
    const float* c2d   = (const float*)d_in[6];
    const float* d2dW  = (const float*)d_in[7];
    float* out = (float*)d_out;
    float* zb  = (float*)d_ws;            // 16B zero block

    hipMemsetAsync(zb, 0, 64, stream);    // ws is poisoned; re-zero every call

    const int blocks = 128 * (HH / TH);   // 768
    dsc5<<<blocks, NT, 0, stream>>>(x, cen_t, dir_t, c2c, p2c, d2c, c2d, d2dW, zb, out);
}

// Round 6
// 731.607 us; speedup vs baseline: 1.2151x; 1.0012x over previous
//
#include <hip/hip_runtime.h>

// DirectionalSeparableConv2D — round 6: remove the 128-VGPR allocator cap.
// r3-r5 all pinned at VGPR_Count=128 with scratch spills (WRITE_SIZE 607/407
// MB vs 147 MB real output): hipcc's default budget for a 384-thread block is
// 128 VGPR, below the kernel's natural ~150-180 need. Occupancy is LDS-bound
// at 2 blocks/CU (12 waves) anyway, so VGPR<=170 is free headroom.
// Single change vs r5: __launch_bounds__(NT, 1) -> budget up to 512, allocator
// allocates what it needs, zero spill code.
//
// Structure (r5): od[24] parked in LDS; convs in <=12-channel chunks; staging
// via __builtin_amdgcn_global_load_lds (16B, no data VGPRs); halo rows and
// cols 48..63 sourced from a 16B zero block in d_ws (no boundary masks).

namespace {
constexpr int HH = 48, WW = 48;
constexpr int CEN_OUT = 32, DIR_OUT = 24;
constexpr int C_IN = 128, C_OUT = 128, HW = HH * WW;
constexpr int TH = 8;            // output rows per block
constexpr int RH = TH + 4;       // staged rows incl. halo (12)
constexpr int RW = 64;           // LDS row stride (floats); cols 48..63 zero
constexpr int QPR = RW / 4;      // 16 quads per row
constexpr int NT = TH * WW;      // 384 threads
}

__device__ __forceinline__ void gl_lds16(const float* g, float* l) {
    __builtin_amdgcn_global_load_lds(
        (const __attribute__((address_space(1))) unsigned int*)g,
        (__attribute__((address_space(3))) unsigned int*)l,
        16, 0, 0);
}

// Stage C channels [c0,c0+C) into xsf, rows h0-2..h0+9. Halo rows and the
// 16-col pad read from the 16B zero block zb.
template <int C>
__device__ __forceinline__ void stage(float* __restrict__ xsf,
                                      const float* __restrict__ xb,
                                      const float* __restrict__ zb,
                                      int c0, int h0, int tid) {
    constexpr int ITEMS = C * RH * QPR;
    constexpr int PT = ITEMS / NT;          // 12ch: 6, 8ch: 4 (exact)
    static_assert(ITEMS % NT == 0, "stage divisibility");
#pragma unroll
    for (int k = 0; k < PT; ++k) {
        int i = tid + k * NT;
        int q = i & (QPR - 1);
        int rc = i >> 4;
        int r = rc % RH;
        int c = rc / RH;
        int gh = h0 - 2 + r;
        bool ok = ((unsigned)gh < (unsigned)HH) && (q < 12);
        const float* src = ok ? (xb + (size_t)(c0 + c) * HW + gh * WW + q * 4) : zb;
        gl_lds16(src, xsf + (size_t)i * 4);
    }
}

// ---- conv macros: fill y[0..N) from xs chunk; weight channel base CB ----
#define CONV3(N, CB)                                                          \
    do {                                                                      \
        _Pragma("unroll") for (int c = 0; c < (N); ++c) {                     \
            float a = 0.f;                                                    \
            _Pragma("unroll") for (int i = 0; i < 3; ++i)                     \
                _Pragma("unroll") for (int j = 0; j < 3; ++j)                 \
                    a += cen_t[((CB) + c) * 9 + i * 3 + j] *                  \
                         xs[c][hl + 1 + i][woff[j + 1]];                      \
            y[c] = a;                                                         \
        }                                                                     \
    } while (0)

#define CONVDIR(CB, ROW, COL)                                                 \
    do {                                                                      \
        _Pragma("unroll") for (int c = 0; c < 12; ++c) {                      \
            float a = 0.f;                                                    \
            _Pragma("unroll") for (int i = 0; i < 5; ++i)                     \
                a += dir_t[((CB) + c) * 5 + i] * xs[c][ROW][COL];             \
            y[c] = a;                                                         \
        }                                                                     \
    } while (0)

// ---- fold macros ----
#define FOLD_CEN(CB, N)                                                       \
    do {                                                                      \
        _Pragma("unroll") for (int o = 0; o < CEN_OUT; ++o) {                 \
            float a = cen_acc[o];                                             \
            _Pragma("unroll") for (int c = 0; c < (N); ++c)                   \
                a += c2c[o * 32 + (CB) + c] * y[c];                           \
            cen_acc[o] = a;                                                   \
        }                                                                     \
        _Pragma("unroll") for (int o = 0; o < DIR_OUT; ++o) {                 \
            float a = od[o];                                                  \
            _Pragma("unroll") for (int c = 0; c < (N); ++c)                   \
                a += c2d[o * 32 + (CB) + c] * y[c];                           \
            od[o] = a;                                                        \
        }                                                                     \
    } while (0)

#define FOLD_DIR0(W2C)                                                        \
    do {                                                                      \
        _Pragma("unroll") for (int o = 0; o < CEN_OUT; ++o) {                 \
            float a = cen_acc[o];                                             \
            _Pragma("unroll") for (int c = 0; c < 12; ++c)                    \
                a += (W2C)[o * 24 + c] * y[c];                                \
            cen_acc[o] = a;                                                   \
        }                                                                     \
        _Pragma("unroll") for (int o = 0; o < DIR_OUT; ++o) {                 \
            float a = odl[o][tid];                                            \
            _Pragma("unroll") for (int c = 0; c < 12; ++c)                    \
                a += d2dW[o * 24 + c] * y[c];                                 \
            da[o] = a;                                                        \
        }                                                                     \
    } while (0)

#define FOLD_DIR1(W2C, G)                                                     \
    do {                                                                      \
        _Pragma("unroll") for (int o = 0; o < CEN_OUT; ++o) {                 \
            float a = cen_acc[o];                                             \
            _Pragma("unroll") for (int c = 0; c < 12; ++c)                    \
                a += (W2C)[o * 24 + 12 + c] * y[c];                           \
            cen_acc[o] = a;                                                   \
        }                                                                     \
        _Pragma("unroll") for (int o = 0; o < DIR_OUT; ++o) {                 \
            float a = da[o];                                                  \
            _Pragma("unroll") for (int c = 0; c < 12; ++c)                    \
                a += d2dW[o * 24 + 12 + c] * y[c];                            \
            ob[(size_t)(CEN_OUT + (G) * DIR_OUT + o) * HW + pix] = a;         \
        }                                                                     \
    } while (0)

__global__ __launch_bounds__(NT, 1) void dsc6(
    const float* __restrict__ x,
    const float* __restrict__ cen_t,   // [32,3,3]
    const float* __restrict__ dir_t,   // [24,5]
    const float* __restrict__ c2c,     // [32,32]
    const float* __restrict__ p2c,     // [32,24]
    const float* __restrict__ d2c,     // [32,24]
    const float* __restrict__ c2d,     // [24,32]
    const float* __restrict__ d2dW,    // [24,24]
    const float* __restrict__ zb,      // 16B zero block (d_ws)
    float* __restrict__ out)
{
    __shared__ float xs[12][RH][RW];        // 36864 B
    __shared__ float odl[DIR_OUT][NT];      // 36864 B  (total 73728)
    float* xsf = &xs[0][0][0];

    const int tid = threadIdx.x;
    const int w  = tid % WW;
    const int hl = tid / WW;                 // 0..7
    const int b  = blockIdx.x / (HH / TH);
    const int h0 = (blockIdx.x % (HH / TH)) * TH;
    const int h  = h0 + hl;
    const float* __restrict__ xb = x   + (size_t)b * C_IN  * HW;
    float* __restrict__       ob = out + (size_t)b * C_OUT * HW;
    const int pix = h * WW + w;

    int woff[5];
#pragma unroll
    for (int i = 0; i < 5; ++i) {
        int ww2 = w + i - 2;
        woff[i] = ((unsigned)ww2 < (unsigned)WW) ? ww2 : 48;
    }

    float cen_acc[CEN_OUT], od[DIR_OUT], da[DIR_OUT], y[12];
#pragma unroll
    for (int o = 0; o < CEN_OUT; ++o) cen_acc[o] = 0.f;
#pragma unroll
    for (int o = 0; o < DIR_OUT; ++o) od[o] = 0.f;

    // ================= cen phase: chunks 12,12,8 =================
    stage<12>(xsf, xb, zb, 0, h0, tid);
    __syncthreads();
    CONV3(12, 0);
    __syncthreads();

    stage<12>(xsf, xb, zb, 12, h0, tid);
    FOLD_CEN(0, 12);
    __syncthreads();
    CONV3(12, 12);
    __syncthreads();

    stage<8>(xsf, xb, zb, 24, h0, tid);
    FOLD_CEN(12, 12);
    __syncthreads();
    CONV3(8, 24);
    __syncthreads();

    // ================= h group (ch 32..55) =================
    stage<12>(xsf, xb, zb, 32, h0, tid);
    FOLD_CEN(24, 8);
#pragma unroll
    for (int o = 0; o < DIR_OUT; ++o) odl[o][tid] = od[o];   // od -> LDS
    __syncthreads();
    CONVDIR(0, hl + 2, woff[i]);
    __syncthreads();

    stage<12>(xsf, xb, zb, 44, h0, tid);
    FOLD_DIR0(p2c);
    __syncthreads();
    CONVDIR(12, hl + 2, woff[i]);
    __syncthreads();

    // ================= v group (ch 56..79) =================
    stage<12>(xsf, xb, zb, 56, h0, tid);
    FOLD_DIR1(p2c, 0);
    __syncthreads();
    CONVDIR(0, hl + i, w);
    __syncthreads();

    stage<12>(xsf, xb, zb, 68, h0, tid);
    FOLD_DIR0(p2c);
    __syncthreads();
    CONVDIR(12, hl + i, w);
    __syncthreads();

    // ================= d1 group (ch 80..103) =================
    stage<12>(xsf, xb, zb, 80, h0, tid);
    FOLD_DIR1(p2c, 1);
    __syncthreads();
    CONVDIR(0, hl + i, woff[i]);
    __syncthreads();

    stage<12>(xsf, xb, zb, 92, h0, tid);
    FOLD_DIR0(d2c);
    __syncthreads();
    CONVDIR(12, hl + i, woff[i]);
    __syncthreads();

    // ================= d2 group (ch 104..127) =================
    stage<12>(xsf, xb, zb, 104, h0, tid);
    FOLD_DIR1(d2c, 2);
    __syncthreads();
    CONVDIR(0, hl + i, woff[4 - i]);
    __syncthreads();

    stage<12>(xsf, xb, zb, 116, h0, tid);
    FOLD_DIR0(d2c);
    __syncthreads();
    CONVDIR(12, hl + i, woff[4 - i]);

    // ================= epilogue =================
    FOLD_DIR1(d2c, 3);
#pragma unroll
    for (int o = 0; o < CEN_OUT; ++o) ob[(size_t)o * HW + pix] = cen_acc[o];
}

extern "C" void kernel_launch(void* const* d_in, const int* in_sizes, int n_in,
                              void* d_out, int out_size, void* d_ws, size_t ws_size,
                              hipStream_t stream) {
    const float* x     = (const float*)d_in[0];
    const float* cen_t = (const float*)d_in[1];
    const float* dir_t = (const float*)d_in[2];
    const float* c2c   = (const float*)d_in[3];
    const float* p2c   = (const float*)d_in[4];
    const float* d2c   = (const float*)d_in[5];
    const float* c2d   = (const float*)d_in[6];
    const float* d2dW  = (const float*)d_in[7];
    float* out = (float*)d_out;
    float* zb  = (float*)d_ws;            // 16B zero block

    hipMemsetAsync(zb, 0, 64, stream);    // ws is poisoned; re-zero every call

    const int blocks = 128 * (HH / TH);   // 768
    dsc6<<<blocks, NT, 0, stream>>>(x, cen_t, dir_t, c2c, p2c, d2c, c2d, d2dW, zb, out);
}

// Round 7
// 246.259 us; speedup vs baseline: 3.6098x; 2.9709x over previous
//
#include <hip/hip_runtime.h>
#include <hip/hip_bf16.h>

// DirectionalSeparableConv2D — round 7: two-phase factorization.
// r4-r6 plateaued at ~732us: monolithic kernel = 21 barrier phases, 2
// blocks/CU, ~100-float live state the allocator spills regardless of
// launch bounds (WRITE 407 MB vs 147 real; FETCH clean at ideal 225 MB).
// New structure:
//   k0 build_MT: fold all 5 mix matrices into dense M_T[128c][128o] fp32.
//   k1 dwconv:   depthwise convs, 1 block per (b,c) 48x48 plane (576 thr,
//                no LDS, no barriers, plane lives in L1), y written bf16.
//   k2 mix:      out[128,P] = M^T-applied GEMM per 64-pixel tile; y tile in
//                LDS, 4 waves x 32 out-ch, lane=pixel, M_T via wave-uniform
//                s_load (transposed layout -> s_load_dwordx16).
// y (75.5 MB) + M_T (64 KB) in d_ws; falls back to the r6 kernel if ws is
// too small.

namespace {
constexpr int HH = 48, WW = 48;
constexpr int CEN_OUT = 32, DIR_OUT = 24;
constexpr int C_IN = 128, C_OUT = 128, HW = HH * WW;   // 2304
constexpr int NB = 128;                                 // batch
constexpr size_t Y_ELEMS = (size_t)NB * C_IN * HW;      // 37.7M
constexpr size_t Y_BYTES = Y_ELEMS * 2;                 // bf16
constexpr size_t MT_BYTES = 128 * 128 * 4;
constexpr int TILE = 64;                                // pixels per mix tile
constexpr int TPI = HW / TILE;                          // 36 tiles per image
}

// ======================= k0: build M_T[c][o] =======================
__global__ void build_MT(const float* __restrict__ c2c, const float* __restrict__ p2c,
                         const float* __restrict__ d2c, const float* __restrict__ c2d,
                         const float* __restrict__ d2dW, float* __restrict__ MT) {
    int t = blockIdx.x * 256 + threadIdx.x;
    if (t >= 128 * 128) return;
    int o = t & 127, c = t >> 7;
    float v;
    if (o < 32) {                       // out_cen rows
        if (c < 32)       v = c2c[o * 32 + c];
        else if (c < 56)  v = p2c[o * 24 + c - 32];
        else if (c < 80)  v = p2c[o * 24 + c - 56];
        else if (c < 104) v = d2c[o * 24 + c - 80];
        else              v = d2c[o * 24 + c - 104];
    } else {                            // dir group g rows
        int g = (o - 32) / 24, oo = (o - 32) % 24;
        if (c < 32) v = c2d[oo * 32 + c];
        else {
            int gc = (c - 32) / 24, cc = (c - 32) % 24;
            v = (gc == g) ? d2dW[oo * 24 + cc] : 0.f;
        }
    }
    MT[c * 128 + o] = v;
}

// ======================= k1: depthwise conv -> y (bf16) =======================
__device__ __forceinline__ float ldm(const float* __restrict__ p, int r, int col) {
    bool ok = ((unsigned)r < (unsigned)HH) & ((unsigned)col < (unsigned)WW);
    return ok ? p[r * WW + col] : 0.f;
}
__device__ __forceinline__ ushort f2bf(float f) {
    __hip_bfloat16 h = __float2bfloat16(f);
    return *reinterpret_cast<ushort*>(&h);
}

__global__ __launch_bounds__(576) void dsc_dwconv(
    const float* __restrict__ x,
    const float* __restrict__ cen_t,   // [32,3,3]
    const float* __restrict__ dir_t,   // [24,5]
    ushort* __restrict__ y)            // bf16 [b*128+c][2304]
{
    const int bid = blockIdx.x;        // = b*128 + c
    const int c   = bid & 127;
    const int tid = threadIdx.x;
    const int row = tid / 12;
    const int w0  = (tid % 12) * 4;
    const float* __restrict__ p = x + (size_t)bid * HW;

    float o0 = 0.f, o1 = 0.f, o2 = 0.f, o3 = 0.f;

    if (c < 32) {                      // 3x3 center
#pragma unroll
        for (int i = 0; i < 3; ++i) {
            int r = row + i - 1;
            float v[6];
#pragma unroll
            for (int j = 0; j < 6; ++j) v[j] = ldm(p, r, w0 + j - 1);
            float k0 = cen_t[c * 9 + i * 3 + 0];
            float k1 = cen_t[c * 9 + i * 3 + 1];
            float k2 = cen_t[c * 9 + i * 3 + 2];
            o0 += k0 * v[0] + k1 * v[1] + k2 * v[2];
            o1 += k0 * v[1] + k1 * v[2] + k2 * v[3];
            o2 += k0 * v[2] + k1 * v[3] + k2 * v[4];
            o3 += k0 * v[3] + k1 * v[4] + k2 * v[5];
        }
    } else if (c < 56) {               // horizontal 1x5
        int cd = c - 32;
        float v[8];
#pragma unroll
        for (int j = 0; j < 8; ++j) v[j] = ldm(p, row, w0 + j - 2);
#pragma unroll
        for (int i = 0; i < 5; ++i) {
            float t = dir_t[cd * 5 + i];
            o0 += t * v[i]; o1 += t * v[i + 1]; o2 += t * v[i + 2]; o3 += t * v[i + 3];
        }
    } else if (c < 80) {               // vertical 5x1 (aligned float4 rows)
        int cd = c - 56;
#pragma unroll
        for (int i = 0; i < 5; ++i) {
            int r = row + i - 2;
            float4 vq;
            if ((unsigned)r < (unsigned)HH) vq = *(const float4*)(p + r * WW + w0);
            else vq = float4{0.f, 0.f, 0.f, 0.f};
            float t = dir_t[cd * 5 + i];
            o0 += t * vq.x; o1 += t * vq.y; o2 += t * vq.z; o3 += t * vq.w;
        }
    } else if (c < 104) {              // diagonal: x[h+i-2][w+i-2]
        int cd = c - 80;
#pragma unroll
        for (int i = 0; i < 5; ++i) {
            int r = row + i - 2;
            float t = dir_t[cd * 5 + i];
            o0 += t * ldm(p, r, w0 + 0 + i - 2);
            o1 += t * ldm(p, r, w0 + 1 + i - 2);
            o2 += t * ldm(p, r, w0 + 2 + i - 2);
            o3 += t * ldm(p, r, w0 + 3 + i - 2);
        }
    } else {                           // anti-diagonal: x[h+i-2][w+2-i]
        int cd = c - 104;
#pragma unroll
        for (int i = 0; i < 5; ++i) {
            int r = row + i - 2;
            float t = dir_t[cd * 5 + i];
            o0 += t * ldm(p, r, w0 + 0 + 2 - i);
            o1 += t * ldm(p, r, w0 + 1 + 2 - i);
            o2 += t * ldm(p, r, w0 + 2 + 2 - i);
            o3 += t * ldm(p, r, w0 + 3 + 2 - i);
        }
    }

    ushort4 s = {f2bf(o0), f2bf(o1), f2bf(o2), f2bf(o3)};
    *(ushort4*)&y[(size_t)bid * HW + row * WW + w0] = s;
}

// ======================= k2: pointwise 128x128 mix =======================
__global__ __launch_bounds__(256) void dsc_mix(
    const ushort* __restrict__ y,      // bf16 [b*128+c][2304]
    const float* __restrict__ MT,      // [128c][128o]
    float* __restrict__ out)
{
    __shared__ ushort yl[128][72];     // bf16 tile, padded stride (16B-mult)

    const int tid  = threadIdx.x;
    const int b    = blockIdx.x / TPI;
    const int p0   = (blockIdx.x % TPI) * TILE;
    const ushort* __restrict__ yb = y + (size_t)b * C_IN * HW + p0;

    // stage: 128 ch x 64 pix bf16; 8 threads per channel-row, 16B each
    {
        const int cb = tid >> 3;
        const int px = (tid & 7) * 8;
#pragma unroll
        for (int k = 0; k < 4; ++k) {
            int cc = cb + k * 32;
            uint4 v = *(const uint4*)(yb + (size_t)cc * HW + px);
            *(uint4*)&yl[cc][px] = v;
        }
    }
    __syncthreads();

    const int wid  = __builtin_amdgcn_readfirstlane(tid >> 6);  // 0..3
    const int lane = tid & 63;
    const float* __restrict__ Mw = MT + wid * 32;   // this wave's 32 out-ch

    float acc[32];
#pragma unroll
    for (int oi = 0; oi < 32; ++oi) acc[oi] = 0.f;

    for (int cc = 0; cc < 128; ++cc) {
        float v = __uint_as_float(((unsigned)yl[cc][lane]) << 16);
        const float* __restrict__ m = Mw + cc * 128;
#pragma unroll
        for (int oi = 0; oi < 32; ++oi) acc[oi] += m[oi] * v;
    }

    float* __restrict__ ob = out + (size_t)b * C_OUT * HW + p0 + lane;
#pragma unroll
    for (int oi = 0; oi < 32; ++oi)
        ob[(size_t)(wid * 32 + oi) * HW] = acc[oi];
}

// ======================= fallback (r6 kernel, used if ws too small) =======================
namespace fb {
constexpr int TH = 8, RH = 12, RW = 64, QPR = 16, NT = 384;

__device__ __forceinline__ void gl_lds16(const float* g, float* l) {
    __builtin_amdgcn_global_load_lds(
        (const __attribute__((address_space(1))) unsigned int*)g,
        (__attribute__((address_space(3))) unsigned int*)l, 16, 0, 0);
}
template <int C>
__device__ __forceinline__ void stage(float* __restrict__ xsf,
                                      const float* __restrict__ xb,
                                      const float* __restrict__ zb,
                                      int c0, int h0, int tid) {
    constexpr int ITEMS = C * RH * QPR;
    constexpr int PT = ITEMS / NT;
#pragma unroll
    for (int k = 0; k < PT; ++k) {
        int i = tid + k * NT;
        int q = i & (QPR - 1);
        int rc = i >> 4;
        int r = rc % RH;
        int c = rc / RH;
        int gh = h0 - 2 + r;
        bool ok = ((unsigned)gh < (unsigned)HH) && (q < 12);
        const float* src = ok ? (xb + (size_t)(c0 + c) * HW + gh * WW + q * 4) : zb;
        gl_lds16(src, xsf + (size_t)i * 4);
    }
}

#define CONV3(N, CB)                                                          \
    do {                                                                      \
        _Pragma("unroll") for (int c = 0; c < (N); ++c) {                     \
            float a = 0.f;                                                    \
            _Pragma("unroll") for (int i = 0; i < 3; ++i)                     \
                _Pragma("unroll") for (int j = 0; j < 3; ++j)                 \
                    a += cen_t[((CB) + c) * 9 + i * 3 + j] *                  \
                         xs[c][hl + 1 + i][woff[j + 1]];                      \
            y[c] = a;                                                         \
        }                                                                     \
    } while (0)
#define CONVDIR(CB, ROW, COL)                                                 \
    do {                                                                      \
        _Pragma("unroll") for (int c = 0; c < 12; ++c) {                      \
            float a = 0.f;                                                    \
            _Pragma("unroll") for (int i = 0; i < 5; ++i)                     \
                a += dir_t[((CB) + c) * 5 + i] * xs[c][ROW][COL];             \
            y[c] = a;                                                         \
        }                                                                     \
    } while (0)
#define FOLD_CEN(CB, N)                                                       \
    do {                                                                      \
        _Pragma("unroll") for (int o = 0; o < CEN_OUT; ++o) {                 \
            float a = cen_acc[o];                                             \
            _Pragma("unroll") for (int c = 0; c < (N); ++c)                   \
                a += c2c[o * 32 + (CB) + c] * y[c];                           \
            cen_acc[o] = a;                                                   \
        }                                                                     \
        _Pragma("unroll") for (int o = 0; o < DIR_OUT; ++o) {                 \
            float a = od[o];                                                  \
            _Pragma("unroll") for (int c = 0; c < (N); ++c)                   \
                a += c2d[o * 32 + (CB) + c] * y[c];                           \
            od[o] = a;                                                        \
        }                                                                     \
    } while (0)
#define FOLD_DIR0(W2C)                                                        \
    do {                                                                      \
        _Pragma("unroll") for (int o = 0; o < CEN_OUT; ++o) {                 \
            float a = cen_acc[o];                                             \
            _Pragma("unroll") for (int c = 0; c < 12; ++c)                    \
                a += (W2C)[o * 24 + c] * y[c];                                \
            cen_acc[o] = a;                                                   \
        }                                                                     \
        _Pragma("unroll") for (int o = 0; o < DIR_OUT; ++o) {                 \
            float a = odl[o][tid];                                            \
            _Pragma("unroll") for (int c = 0; c < 12; ++c)                    \
                a += d2dW[o * 24 + c] * y[c];                                 \
            da[o] = a;                                                        \
        }                                                                     \
    } while (0)
#define FOLD_DIR1(W2C, G)                                                     \
    do {                                                                      \
        _Pragma("unroll") for (int o = 0; o < CEN_OUT; ++o) {                 \
            float a = cen_acc[o];                                             \
            _Pragma("unroll") for (int c = 0; c < 12; ++c)                    \
                a += (W2C)[o * 24 + 12 + c] * y[c];                           \
            cen_acc[o] = a;                                                   \
        }                                                                     \
        _Pragma("unroll") for (int o = 0; o < DIR_OUT; ++o) {                 \
            float a = da[o];                                                  \
            _Pragma("unroll") for (int c = 0; c < 12; ++c)                    \
                a += d2dW[o * 24 + 12 + c] * y[c];                            \
            ob[(size_t)(CEN_OUT + (G) * DIR_OUT + o) * HW + pix] = a;         \
        }                                                                     \
    } while (0)

__global__ __launch_bounds__(NT) void dsc6(
    const float* __restrict__ x, const float* __restrict__ cen_t,
    const float* __restrict__ dir_t, const float* __restrict__ c2c,
    const float* __restrict__ p2c, const float* __restrict__ d2c,
    const float* __restrict__ c2d, const float* __restrict__ d2dW,
    const float* __restrict__ zb, float* __restrict__ out)
{
    __shared__ float xs[12][RH][RW];
    __shared__ float odl[DIR_OUT][NT];
    float* xsf = &xs[0][0][0];
    const int tid = threadIdx.x;
    const int w  = tid % WW;
    const int hl = tid / WW;
    const int b  = blockIdx.x / (HH / TH);
    const int h0 = (blockIdx.x % (HH / TH)) * TH;
    const int h  = h0 + hl;
    const float* __restrict__ xb = x   + (size_t)b * C_IN  * HW;
    float* __restrict__       ob = out + (size_t)b * C_OUT * HW;
    const int pix = h * WW + w;
    int woff[5];
#pragma unroll
    for (int i = 0; i < 5; ++i) {
        int ww2 = w + i - 2;
        woff[i] = ((unsigned)ww2 < (unsigned)WW) ? ww2 : 48;
    }
    float cen_acc[CEN_OUT], od[DIR_OUT], da[DIR_OUT], y[12];
#pragma unroll
    for (int o = 0; o < CEN_OUT; ++o) cen_acc[o] = 0.f;
#pragma unroll
    for (int o = 0; o < DIR_OUT; ++o) od[o] = 0.f;

    stage<12>(xsf, xb, zb, 0, h0, tid);
    __syncthreads();
    CONV3(12, 0);
    __syncthreads();
    stage<12>(xsf, xb, zb, 12, h0, tid);
    FOLD_CEN(0, 12);
    __syncthreads();
    CONV3(12, 12);
    __syncthreads();
    stage<8>(xsf, xb, zb, 24, h0, tid);
    FOLD_CEN(12, 12);
    __syncthreads();
    CONV3(8, 24);
    __syncthreads();
    stage<12>(xsf, xb, zb, 32, h0, tid);
    FOLD_CEN(24, 8);
#pragma unroll
    for (int o = 0; o < DIR_OUT; ++o) odl[o][tid] = od[o];
    __syncthreads();
    CONVDIR(0, hl + 2, woff[i]);
    __syncthreads();
    stage<12>(xsf, xb, zb, 44, h0, tid);
    FOLD_DIR0(p2c);
    __syncthreads();
    CONVDIR(12, hl + 2, woff[i]);
    __syncthreads();
    stage<12>(xsf, xb, zb, 56, h0, tid);
    FOLD_DIR1(p2c, 0);
    __syncthreads();
    CONVDIR(0, hl + i, w);
    __syncthreads();
    stage<12>(xsf, xb, zb, 68, h0, tid);
    FOLD_DIR0(p2c);
    __syncthreads();
    CONVDIR(12, hl + i, w);
    __syncthreads();
    stage<12>(xsf, xb, zb, 80, h0, tid);
    FOLD_DIR1(p2c, 1);
    __syncthreads();
    CONVDIR(0, hl + i, woff[i]);
    __syncthreads();
    stage<12>(xsf, xb, zb, 92, h0, tid);
    FOLD_DIR0(d2c);
    __syncthreads();
    CONVDIR(12, hl + i, woff[i]);
    __syncthreads();
    stage<12>(xsf, xb, zb, 104, h0, tid);
    FOLD_DIR1(d2c, 2);
    __syncthreads();
    CONVDIR(0, hl + i, woff[4 - i]);
    __syncthreads();
    stage<12>(xsf, xb, zb, 116, h0, tid);
    FOLD_DIR0(d2c);
    __syncthreads();
    CONVDIR(12, hl + i, woff[4 - i]);
    FOLD_DIR1(d2c, 3);
#pragma unroll
    for (int o = 0; o < CEN_OUT; ++o) ob[(size_t)o * HW + pix] = cen_acc[o];
}
}  // namespace fb

// ======================= launcher =======================
extern "C" void kernel_launch(void* const* d_in, const int* in_sizes, int n_in,
                              void* d_out, int out_size, void* d_ws, size_t ws_size,
                              hipStream_t stream) {
    const float* x     = (const float*)d_in[0];
    const float* cen_t = (const float*)d_in[1];
    const float* dir_t = (const float*)d_in[2];
    const float* c2c   = (const float*)d_in[3];
    const float* p2c   = (const float*)d_in[4];
    const float* d2c   = (const float*)d_in[5];
    const float* c2d   = (const float*)d_in[6];
    const float* d2dW  = (const float*)d_in[7];
    float* out = (float*)d_out;

    if (ws_size >= Y_BYTES + MT_BYTES) {
        ushort* y  = (ushort*)d_ws;
        float*  MT = (float*)((char*)d_ws + Y_BYTES);

        build_MT<<<64, 256, 0, stream>>>(c2c, p2c, d2c, c2d, d2dW, MT);
        dsc_dwconv<<<NB * C_IN, 576, 0, stream>>>(x, cen_t, dir_t, y);
        dsc_mix<<<NB * TPI, 256, 0, stream>>>(y, MT, out);
    } else {
        float* zb = (float*)d_ws;
        hipMemsetAsync(zb, 0, 64, stream);
        fb::dsc6<<<NB * (HH / fb::TH), fb::NT, 0, stream>>>(
            x, cen_t, dir_t, c2c, p2c, d2c, c2d, d2dW, zb, out);
    }
}

// Round 8
// 123.072 us; speedup vs baseline: 7.2229x; 2.0009x over previous
//
#include <hip/hip_runtime.h>
#include <hip/hip_bf16.h>

// DirectionalSeparableConv2D — round 8.
// r7 (246us): dwconv 149us latency-bound (scalar masked loads, VGPR=16,
// ~2 loads in flight); mix 95us on the fp32 VALU (floor 61us for 9.7 GFLOP).
// This round:
//   k1 dwconv: LDS-staged plane (1 coalesced float4/thread, zero-padded
//              borders -> maskless taps from LDS). 227 MB -> ~36us floor.
//   k2 mix:    bf16 MFMA 16x16x32. A = M_bf[o][c] (global, L2-hot 32KB);
//              B = y tile transposed into LDS yT[64p][136c] at stage time
//              (ds_write_u16, conflict-free); D cols=pixels -> coalesced.
// Error: y bf16 (as r7) + M bf16 -> ~0.012 << 0.033 threshold.

namespace {
constexpr int HH = 48, WW = 48;
constexpr int CEN_OUT = 32, DIR_OUT = 24;
constexpr int C_IN = 128, C_OUT = 128, HW = HH * WW;   // 2304
constexpr int NB = 128;
constexpr size_t Y_ELEMS = (size_t)NB * C_IN * HW;
constexpr size_t Y_BYTES = Y_ELEMS * 2;                 // bf16
constexpr size_t M_BYTES = 128 * 128 * 2;               // bf16
constexpr int TILE = 64;                                // pixels per mix tile
constexpr int TPI = HW / TILE;                          // 36
}

typedef __attribute__((ext_vector_type(8))) short bf16x8;
typedef __attribute__((ext_vector_type(4))) float f32x4;

__device__ __forceinline__ ushort f2bf(float f) {
    __hip_bfloat16 h = __float2bfloat16(f);
    return *reinterpret_cast<ushort*>(&h);
}

// ======================= k0: build M_bf[o][c] (bf16) =======================
__global__ void build_M(const float* __restrict__ c2c, const float* __restrict__ p2c,
                        const float* __restrict__ d2c, const float* __restrict__ c2d,
                        const float* __restrict__ d2dW, ushort* __restrict__ Mbf) {
    int t = blockIdx.x * 256 + threadIdx.x;
    if (t >= 128 * 128) return;
    int o = t & 127, c = t >> 7;
    float v;
    if (o < 32) {
        if (c < 32)       v = c2c[o * 32 + c];
        else if (c < 56)  v = p2c[o * 24 + c - 32];
        else if (c < 80)  v = p2c[o * 24 + c - 56];
        else if (c < 104) v = d2c[o * 24 + c - 80];
        else              v = d2c[o * 24 + c - 104];
    } else {
        int g = (o - 32) / 24, oo = (o - 32) % 24;
        if (c < 32) v = c2d[oo * 32 + c];
        else {
            int gc = (c - 32) / 24, cc = (c - 32) % 24;
            v = (gc == g) ? d2dW[oo * 24 + cc] : 0.f;
        }
    }
    Mbf[o * 128 + c] = f2bf(v);
}

// ======================= k1: depthwise conv -> y (bf16) =======================
// Block per (b,c) plane; 576 threads. Plane staged to LDS with zero borders.
namespace dw {
constexpr int PR = 56;            // padded row stride (floats), 224B = 14*16
constexpr int NROW = 52;          // rows -2..49
constexpr int NQ = NROW * PR / 4; // 728 quads
}

__global__ __launch_bounds__(576) void dsc_dwconv(
    const float* __restrict__ x,
    const float* __restrict__ cen_t,   // [32,3,3]
    const float* __restrict__ dir_t,   // [24,5]
    ushort* __restrict__ y)            // bf16 [b*128+c][2304]
{
    __shared__ float xp[dw::NROW * dw::PR];   // 11648 B

    const int bid = blockIdx.x;        // b*128 + c
    const int c   = bid & 127;
    const int tid = threadIdx.x;

    // zero whole tile (728 quads over 576 threads)
    {
        float4 z = {0.f, 0.f, 0.f, 0.f};
        ((float4*)xp)[tid] = z;
        if (tid < dw::NQ - 576) ((float4*)xp)[576 + tid] = z;
    }
    __syncthreads();

    // stage plane: tid == linear quad index (12 quads/row * 48 rows = 576)
    {
        const int r = tid / 12, q = tid % 12;
        float4 v = *(const float4*)(x + (size_t)bid * HW + tid * 4);
        *(float4*)&xp[(r + 2) * dw::PR + 4 + q * 4] = v;
    }
    __syncthreads();

    const int row = tid / 12;
    const int w0  = (tid % 12) * 4;
    float o0 = 0.f, o1 = 0.f, o2 = 0.f, o3 = 0.f;

#define XP(r_, c_) xp[(r_) * dw::PR + (c_)]

    if (c < 32) {                      // 3x3: x[h+i-1][w+j-1]
#pragma unroll
        for (int i = 0; i < 3; ++i)
#pragma unroll
            for (int j = 0; j < 3; ++j) {
                float k = cen_t[c * 9 + i * 3 + j];
                int r = row + i + 1, cc = w0 + j + 3;
                o0 += k * XP(r, cc + 0);
                o1 += k * XP(r, cc + 1);
                o2 += k * XP(r, cc + 2);
                o3 += k * XP(r, cc + 3);
            }
    } else if (c < 56) {               // h: x[h][w+i-2]
        int cd = c - 32;
#pragma unroll
        for (int i = 0; i < 5; ++i) {
            float t = dir_t[cd * 5 + i];
            int cc = w0 + i + 2;
            o0 += t * XP(row + 2, cc + 0);
            o1 += t * XP(row + 2, cc + 1);
            o2 += t * XP(row + 2, cc + 2);
            o3 += t * XP(row + 2, cc + 3);
        }
    } else if (c < 80) {               // v: x[h+i-2][w]  (aligned float4)
        int cd = c - 56;
#pragma unroll
        for (int i = 0; i < 5; ++i) {
            float t = dir_t[cd * 5 + i];
            float4 vq = *(const float4*)&XP(row + i, w0 + 4);
            o0 += t * vq.x; o1 += t * vq.y; o2 += t * vq.z; o3 += t * vq.w;
        }
    } else if (c < 104) {              // d1: x[h+i-2][w+i-2]
        int cd = c - 80;
#pragma unroll
        for (int i = 0; i < 5; ++i) {
            float t = dir_t[cd * 5 + i];
            int cc = w0 + i + 2;
            o0 += t * XP(row + i, cc + 0);
            o1 += t * XP(row + i, cc + 1);
            o2 += t * XP(row + i, cc + 2);
            o3 += t * XP(row + i, cc + 3);
        }
    } else {                           // d2: x[h+i-2][w+2-i]
        int cd = c - 104;
#pragma unroll
        for (int i = 0; i < 5; ++i) {
            float t = dir_t[cd * 5 + i];
            int cc = w0 + 6 - i;
            o0 += t * XP(row + i, cc + 0);
            o1 += t * XP(row + i, cc + 1);
            o2 += t * XP(row + i, cc + 2);
            o3 += t * XP(row + i, cc + 3);
        }
    }
#undef XP

    ushort4 s = {f2bf(o0), f2bf(o1), f2bf(o2), f2bf(o3)};
    *(ushort4*)&y[(size_t)bid * HW + row * WW + w0] = s;
}

// ======================= k2: MFMA pointwise mix =======================
// out[o, 64p] = M[o,c] @ y[c, 64p] per tile. 4 waves x 32 out-ch.
// A-frag (M): lane holds M[o0+(l&15)][kb*32+(l>>4)*8 + 0..7]  (global, 16B)
// B-frag (y): lane holds yT[pf*16+(l&15)][kb*32+(l>>4)*8 + 0..7] (ds_read_b128)
// D: col = lane&15 = pixel, row = (lane>>4)*4+r = out-ch (m89 layout).
__global__ __launch_bounds__(256) void dsc_mix(
    const ushort* __restrict__ y,      // bf16 [b*128+c][2304]
    const ushort* __restrict__ Mbf,    // bf16 [128o][128c]
    float* __restrict__ out)
{
    __shared__ ushort yT[64][136];     // transposed tile, 17408 B

    const int tid = threadIdx.x;
    const int b   = blockIdx.x / TPI;
    const int p0  = (blockIdx.x % TPI) * TILE;
    const int l   = tid & 63;
    const int wv  = tid >> 6;          // 0..3 -> out-ch [wv*32, wv*32+32)

    // ---- A-frags from global (L2-hot 32KB), overlap with staging ----
    bf16x8 afr[2][4];
#pragma unroll
    for (int of = 0; of < 2; ++of)
#pragma unroll
        for (int kb = 0; kb < 4; ++kb) {
            int ro = wv * 32 + of * 16 + (l & 15);
            int co = kb * 32 + (l >> 4) * 8;
            afr[of][kb] = *(const bf16x8*)(Mbf + ro * 128 + co);
        }

    // ---- stage y tile transposed: yT[p][c] ----
    {
        const int c = tid & 127;
        const ushort* src = y + (size_t)b * C_IN * HW + (size_t)c * HW + p0;
#pragma unroll
        for (int k = 0; k < 4; ++k) {
            int oct = (tid >> 7) + k * 2;          // 0..7
            uint4 v = *(const uint4*)(src + oct * 8);
            const ushort* pv = (const ushort*)&v;
#pragma unroll
            for (int i = 0; i < 8; ++i)
                yT[oct * 8 + i][c] = pv[i];
        }
    }
    __syncthreads();

    // ---- MFMA: 2 o-frags x 4 p-frags x 4 K-steps ----
    f32x4 acc[2][4] = {};
#pragma unroll
    for (int kb = 0; kb < 4; ++kb)
#pragma unroll
        for (int pf = 0; pf < 4; ++pf) {
            bf16x8 bfr = *(const bf16x8*)&yT[pf * 16 + (l & 15)][kb * 32 + (l >> 4) * 8];
            acc[0][pf] = __builtin_amdgcn_mfma_f32_16x16x32_bf16(afr[0][kb], bfr, acc[0][pf], 0, 0, 0);
            acc[1][pf] = __builtin_amdgcn_mfma_f32_16x16x32_bf16(afr[1][kb], bfr, acc[1][pf], 0, 0, 0);
        }

    // ---- store ----
    float* __restrict__ ob = out + (size_t)b * C_OUT * HW;
#pragma unroll
    for (int of = 0; of < 2; ++of)
#pragma unroll
        for (int pf = 0; pf < 4; ++pf) {
            int o_base = wv * 32 + of * 16 + (l >> 4) * 4;
            int p = p0 + pf * 16 + (l & 15);
#pragma unroll
            for (int r = 0; r < 4; ++r)
                ob[(size_t)(o_base + r) * HW + p] = acc[of][pf][r];
        }
}

// ======================= fallback (r6 kernel, ws too small) =======================
namespace fb {
constexpr int TH = 8, RH = 12, RW = 64, QPR = 16, NT = 384;

__device__ __forceinline__ void gl_lds16(const float* g, float* l) {
    __builtin_amdgcn_global_load_lds(
        (const __attribute__((address_space(1))) unsigned int*)g,
        (__attribute__((address_space(3))) unsigned int*)l, 16, 0, 0);
}
template <int C>
__device__ __forceinline__ void stage(float* __restrict__ xsf,
                                      const float* __restrict__ xb,
                                      const float* __restrict__ zb,
                                      int c0, int h0, int tid) {
    constexpr int ITEMS = C * RH * QPR;
    constexpr int PT = ITEMS / NT;
#pragma unroll
    for (int k = 0; k < PT; ++k) {
        int i = tid + k * NT;
        int q = i & (QPR - 1);
        int rc = i >> 4;
        int r = rc % RH;
        int c = rc / RH;
        int gh = h0 - 2 + r;
        bool ok = ((unsigned)gh < (unsigned)HH) && (q < 12);
        const float* src = ok ? (xb + (size_t)(c0 + c) * HW + gh * WW + q * 4) : zb;
        gl_lds16(src, xsf + (size_t)i * 4);
    }
}

#define CONV3(N, CB)                                                          \
    do {                                                                      \
        _Pragma("unroll") for (int c = 0; c < (N); ++c) {                     \
            float a = 0.f;                                                    \
            _Pragma("unroll") for (int i = 0; i < 3; ++i)                     \
                _Pragma("unroll") for (int j = 0; j < 3; ++j)                 \
                    a += cen_t[((CB) + c) * 9 + i * 3 + j] *                  \
                         xs[c][hl + 1 + i][woff[j + 1]];                      \
            y[c] = a;                                                         \
        }                                                                     \
    } while (0)
#define CONVDIR(CB, ROW, COL)                                                 \
    do {                                                                      \
        _Pragma("unroll") for (int c = 0; c < 12; ++c) {                      \
            float a = 0.f;                                                    \
            _Pragma("unroll") for (int i = 0; i < 5; ++i)                     \
                a += dir_t[((CB) + c) * 5 + i] * xs[c][ROW][COL];             \
            y[c] = a;                                                         \
        }                                                                     \
    } while (0)
#define FOLD_CEN(CB, N)                                                       \
    do {                                                                      \
        _Pragma("unroll") for (int o = 0; o < CEN_OUT; ++o) {                 \
            float a = cen_acc[o];                                             \
            _Pragma("unroll") for (int c = 0; c < (N); ++c)                   \
                a += c2c[o * 32 + (CB) + c] * y[c];                           \
            cen_acc[o] = a;                                                   \
        }                                                                     \
        _Pragma("unroll") for (int o = 0; o < DIR_OUT; ++o) {                 \
            float a = od[o];                                                  \
            _Pragma("unroll") for (int c = 0; c < (N); ++c)                   \
                a += c2d[o * 32 + (CB) + c] * y[c];                           \
            od[o] = a;                                                        \
        }                                                                     \
    } while (0)
#define FOLD_DIR0(W2C)                                                        \
    do {                                                                      \
        _Pragma("unroll") for (int o = 0; o < CEN_OUT; ++o) {                 \
            float a = cen_acc[o];                                             \
            _Pragma("unroll") for (int c = 0; c < 12; ++c)                    \
                a += (W2C)[o * 24 + c] * y[c];                                \
            cen_acc[o] = a;                                                   \
        }                                                                     \
        _Pragma("unroll") for (int o = 0; o < DIR_OUT; ++o) {                 \
            float a = odl[o][tid];                                            \
            _Pragma("unroll") for (int c = 0; c < 12; ++c)                    \
                a += d2dW[o * 24 + c] * y[c];                                 \
            da[o] = a;                                                        \
        }                                                                     \
    } while (0)
#define FOLD_DIR1(W2C, G)                                                     \
    do {                                                                      \
        _Pragma("unroll") for (int o = 0; o < CEN_OUT; ++o) {                 \
            float a = cen_acc[o];                                             \
            _Pragma("unroll") for (int c = 0; c < 12; ++c)                    \
                a += (W2C)[o * 24 + 12 + c] * y[c];                           \
            cen_acc[o] = a;                                                   \
        }                                                                     \
        _Pragma("unroll") for (int o = 0; o < DIR_OUT; ++o) {                 \
            float a = da[o];                                                  \
            _Pragma("unroll") for (int c = 0; c < 12; ++c)                    \
                a += d2dW[o * 24 + 12 + c] * y[c];                            \
            ob[(size_t)(CEN_OUT + (G) * DIR_OUT + o) * HW + pix] = a;         \
        }                                                                     \
    } while (0)

__global__ __launch_bounds__(NT) void dsc6(
    const float* __restrict__ x, const float* __restrict__ cen_t,
    const float* __restrict__ dir_t, const float* __restrict__ c2c,
    const float* __restrict__ p2c, const float* __restrict__ d2c,
    const float* __restrict__ c2d, const float* __restrict__ d2dW,
    const float* __restrict__ zb, float* __restrict__ out)
{
    __shared__ float xs[12][RH][RW];
    __shared__ float odl[DIR_OUT][NT];
    float* xsf = &xs[0][0][0];
    const int tid = threadIdx.x;
    const int w  = tid % WW;
    const int hl = tid / WW;
    const int b  = blockIdx.x / (HH / TH);
    const int h0 = (blockIdx.x % (HH / TH)) * TH;
    const int h  = h0 + hl;
    const float* __restrict__ xb = x   + (size_t)b * C_IN  * HW;
    float* __restrict__       ob = out + (size_t)b * C_OUT * HW;
    const int pix = h * WW + w;
    int woff[5];
#pragma unroll
    for (int i = 0; i < 5; ++i) {
        int ww2 = w + i - 2;
        woff[i] = ((unsigned)ww2 < (unsigned)WW) ? ww2 : 48;
    }
    float cen_acc[CEN_OUT], od[DIR_OUT], da[DIR_OUT], y[12];
#pragma unroll
    for (int o = 0; o < CEN_OUT; ++o) cen_acc[o] = 0.f;
#pragma unroll
    for (int o = 0; o < DIR_OUT; ++o) od[o] = 0.f;

    stage<12>(xsf, xb, zb, 0, h0, tid);
    __syncthreads();
    CONV3(12, 0);
    __syncthreads();
    stage<12>(xsf, xb, zb, 12, h0, tid);
    FOLD_CEN(0, 12);
    __syncthreads();
    CONV3(12, 12);
    __syncthreads();
    stage<8>(xsf, xb, zb, 24, h0, tid);
    FOLD_CEN(12, 12);
    __syncthreads();
    CONV3(8, 24);
    __syncthreads();
    stage<12>(xsf, xb, zb, 32, h0, tid);
    FOLD_CEN(24, 8);
#pragma unroll
    for (int o = 0; o < DIR_OUT; ++o) odl[o][tid] = od[o];
    __syncthreads();
    CONVDIR(0, hl + 2, woff[i]);
    __syncthreads();
    stage<12>(xsf, xb, zb, 44, h0, tid);
    FOLD_DIR0(p2c);
    __syncthreads();
    CONVDIR(12, hl + 2, woff[i]);
    __syncthreads();
    stage<12>(xsf, xb, zb, 56, h0, tid);
    FOLD_DIR1(p2c, 0);
    __syncthreads();
    CONVDIR(0, hl + i, w);
    __syncthreads();
    stage<12>(xsf, xb, zb, 68, h0, tid);
    FOLD_DIR0(p2c);
    __syncthreads();
    CONVDIR(12, hl + i, w);
    __syncthreads();
    stage<12>(xsf, xb, zb, 80, h0, tid);
    FOLD_DIR1(p2c, 1);
    __syncthreads();
    CONVDIR(0, hl + i, woff[i]);
    __syncthreads();
    stage<12>(xsf, xb, zb, 92, h0, tid);
    FOLD_DIR0(d2c);
    __syncthreads();
    CONVDIR(12, hl + i, woff[i]);
    __syncthreads();
    stage<12>(xsf, xb, zb, 104, h0, tid);
    FOLD_DIR1(d2c, 2);
    __syncthreads();
    CONVDIR(0, hl + i, woff[4 - i]);
    __syncthreads();
    stage<12>(xsf, xb, zb, 116, h0, tid);
    FOLD_DIR0(d2c);
    __syncthreads();
    CONVDIR(12, hl + i, woff[4 - i]);
    FOLD_DIR1(d2c, 3);
#pragma unroll
    for (int o = 0; o < CEN_OUT; ++o) ob[(size_t)o * HW + pix] = cen_acc[o];
}
}  // namespace fb

// ======================= launcher =======================
extern "C" void kernel_launch(void* const* d_in, const int* in_sizes, int n_in,
                              void* d_out, int out_size, void* d_ws, size_t ws_size,
                              hipStream_t stream) {
    const float* x     = (const float*)d_in[0];
    const float* cen_t = (const float*)d_in[1];
    const float* dir_t = (const float*)d_in[2];
    const float* c2c   = (const float*)d_in[3];
    const float* p2c   = (const float*)d_in[4];
    const float* d2c   = (const float*)d_in[5];
    const float* c2d   = (const float*)d_in[6];
    const float* d2dW  = (const float*)d_in[7];
    float* out = (float*)d_out;

    if (ws_size >= Y_BYTES + M_BYTES) {
        ushort* y   = (ushort*)d_ws;
        ushort* Mbf = (ushort*)((char*)d_ws + Y_BYTES);

        build_M<<<64, 256, 0, stream>>>(c2c, p2c, d2c, c2d, d2dW, Mbf);
        dsc_dwconv<<<NB * C_IN, 576, 0, stream>>>(x, cen_t, dir_t, y);
        dsc_mix<<<NB * TPI, 256, 0, stream>>>(y, Mbf, out);
    } else {
        float* zb = (float*)d_ws;
        hipMemsetAsync(zb, 0, 64, stream);
        fb::dsc6<<<NB * (HH / fb::TH), fb::NT, 0, stream>>>(
            x, cen_t, dir_t, c2c, p2c, d2c, c2d, d2dW, zb, out);
    }
}